// Round 1
// baseline (444.770 us; speedup 1.0000x reference)
//
#include <hip/hip_runtime.h>
#include <hip/hip_fp16.h>
#include <cstdint>
#include <cstddef>

#define GLOBAL_AS __attribute__((address_space(1)))
#define LDS_AS    __attribute__((address_space(3)))

typedef __attribute__((ext_vector_type(8))) _Float16 f16x8;
typedef __attribute__((ext_vector_type(4))) float    f32x4;

// ---------------------------------------------------------------------------
// async global->LDS, 16B per lane. Size must be a literal (guide §5).
// ---------------------------------------------------------------------------
__device__ __forceinline__ void gload_lds16(const void* g, void* l) {
    __builtin_amdgcn_global_load_lds((const GLOBAL_AS void*)g,
                                     (LDS_AS void*)l, 16, 0, 0);
}

// fp16 quantizer == reference fp_quantize_ste(exp=5, sig=10): RNE + saturate.
__device__ __forceinline__ __half qcvt(float x) {
    x = fminf(fmaxf(x, -65504.f), 65504.f);
    return __float2half(x);   // v_cvt_f16_f32: RNE, subnormals handled
}

// ---------------------------------------------------------------------------
// Pass 1: fp32 -> fp16 quantization, vectorized (float4 in, 8B out)
// ---------------------------------------------------------------------------
__global__ void quant_f32_to_f16(const float* __restrict__ in,
                                 __half* __restrict__ out, int n4) {
    const int stride = gridDim.x * blockDim.x;
    for (int i = blockIdx.x * blockDim.x + threadIdx.x; i < n4; i += stride) {
        const float4 f = reinterpret_cast<const float4*>(in)[i];
        union { __half h[4]; uint2 u; } p;
        p.h[0] = qcvt(f.x);
        p.h[1] = qcvt(f.y);
        p.h[2] = qcvt(f.z);
        p.h[3] = qcvt(f.w);
        reinterpret_cast<uint2*>(out)[i] = p.u;
    }
}

// ---------------------------------------------------------------------------
// Pass 2: fp16 GEMM, C = A @ B^T + bias.  A: MxK row-major, B: NxK row-major.
// m97 structure: 128x128 tile, BK=32, 4 waves of 64x64, global_load_lds w=16.
// ---------------------------------------------------------------------------
__global__ __launch_bounds__(256) void gemm_f16_qat(
    const __half* __restrict__ A, const __half* __restrict__ B,
    const __half* __restrict__ bias, float* __restrict__ C,
    int M, int N, int K)
{
    __shared__ __half As[128][32];
    __shared__ __half Bs[128][32];

    const int tid  = threadIdx.x;
    const int lane = tid & 63;
    const int wid  = tid >> 6;      // 4 waves
    const int wr   = wid >> 1;      // wave row (0..1)
    const int wc   = wid & 1;       // wave col (0..1)
    const int fr   = lane & 15;     // fragment row/col index
    const int fq   = lane >> 4;     // k-chunk selector (0..3)

    // Bijective XCD-aware swizzle (m204 formula)
    const int nwg = gridDim.x;
    const int qq  = nwg >> 3, rr = nwg & 7;
    const int xcd = blockIdx.x & 7, idx = blockIdx.x >> 3;
    const int wgid = (xcd < rr ? xcd * (qq + 1)
                               : rr * (qq + 1) + (xcd - rr) * qq) + idx;
    const int nbn = N >> 7;
    const int bm = wgid / nbn, bn = wgid % nbn;
    const int tile_m = bm << 7, tile_n = bn << 7;

    // staging: thread t covers 16B at linear LDS byte offset t*16 (+4096 for
    // second half) -> wave-uniform base + lane*16, as global_load_lds requires
    const int arow = tid >> 2;            // 0..63
    const int acol = (tid & 3) << 3;      // 0,8,16,24
    const __half* gA = A + (size_t)(tile_m + arow) * K + acol;
    const __half* gB = B + (size_t)(tile_n + arow) * K + acol;
    __half* lA0 = &As[arow][acol];
    __half* lA1 = &As[arow + 64][acol];
    __half* lB0 = &Bs[arow][acol];
    __half* lB1 = &Bs[arow + 64][acol];
    const size_t rowK64 = (size_t)64 * K;

    f32x4 acc[4][4];
#pragma unroll
    for (int m = 0; m < 4; ++m)
#pragma unroll
        for (int n = 0; n < 4; ++n)
            acc[m][n] = (f32x4){0.f, 0.f, 0.f, 0.f};

    for (int k0 = 0; k0 < K; k0 += 32) {
        gload_lds16(gA + k0,          lA0);
        gload_lds16(gA + rowK64 + k0, lA1);
        gload_lds16(gB + k0,          lB0);
        gload_lds16(gB + rowK64 + k0, lB1);
        __syncthreads();   // drains vmcnt, tiles ready

        f16x8 af[4], bf[4];
#pragma unroll
        for (int m = 0; m < 4; ++m)
            af[m] = *(const f16x8*)&As[wr * 64 + m * 16 + fr][fq * 8];
#pragma unroll
        for (int n = 0; n < 4; ++n)
            bf[n] = *(const f16x8*)&Bs[wc * 64 + n * 16 + fr][fq * 8];

#pragma unroll
        for (int m = 0; m < 4; ++m)
#pragma unroll
            for (int n = 0; n < 4; ++n)
                acc[m][n] = __builtin_amdgcn_mfma_f32_16x16x32_f16(
                    af[m], bf[n], acc[m][n], 0, 0, 0);

        __syncthreads();   // reads done before next overwrite
    }

    // epilogue: C/D layout col=lane&15, row=(lane>>4)*4+reg  (m89-verified)
    float bv[4];
#pragma unroll
    for (int n = 0; n < 4; ++n)
        bv[n] = __half2float(bias[tile_n + wc * 64 + n * 16 + fr]);

#pragma unroll
    for (int m = 0; m < 4; ++m) {
#pragma unroll
        for (int n = 0; n < 4; ++n) {
            const int col = tile_n + wc * 64 + n * 16 + fr;
#pragma unroll
            for (int r = 0; r < 4; ++r) {
                const int row = tile_m + wr * 64 + m * 16 + fq * 4 + r;
                C[(size_t)row * N + col] = acc[m][n][r] + bv[n];
            }
        }
    }
}

// ---------------------------------------------------------------------------
// Insurance fallback if ws_size is too small: fused naive (slow but correct).
// ---------------------------------------------------------------------------
__global__ void qat_gemm_naive(const float* __restrict__ A,
                               const float* __restrict__ B,
                               const float* __restrict__ bias,
                               float* __restrict__ C, int M, int N, int K) {
    const int col = blockIdx.x * blockDim.x + threadIdx.x;
    const int row = blockIdx.y;
    if (col >= N || row >= M) return;
    float s = 0.f;
    for (int k = 0; k < K; ++k) {
        float a = __half2float(qcvt(A[(size_t)row * K + k]));
        float b = __half2float(qcvt(B[(size_t)col * K + k]));
        s += a * b;
    }
    C[(size_t)row * N + col] = s + __half2float(qcvt(bias[col]));
}

// ---------------------------------------------------------------------------
extern "C" void kernel_launch(void* const* d_in, const int* in_sizes, int n_in,
                              void* d_out, int out_size, void* d_ws,
                              size_t ws_size, hipStream_t stream) {
    const float* x = (const float*)d_in[0];
    const float* w = (const float*)d_in[1];
    const float* b = (const float*)d_in[2];
    float* out = (float*)d_out;

    const int xn = in_sizes[0];     // M*K
    const int wn = in_sizes[1];     // N*K
    const int N  = in_sizes[2];     // 4096
    const int K  = wn / N;          // 4096
    const int M  = xn / K;          // 8192

    const size_t need = (size_t)(xn + wn + N) * sizeof(__half);
    const bool tiles_ok = (M % 128 == 0) && (N % 128 == 0) && (K % 32 == 0) &&
                          ((N >> 7) % 1 == 0);

    if (ws_size >= need && tiles_ok) {
        __half* xq = (__half*)d_ws;
        __half* wq = xq + xn;
        __half* bq = wq + wn;

        int blk;
        blk = (xn / 4 + 255) / 256; if (blk > 2048) blk = 2048;
        quant_f32_to_f16<<<blk, 256, 0, stream>>>(x, xq, xn / 4);
        blk = (wn / 4 + 255) / 256; if (blk > 2048) blk = 2048;
        quant_f32_to_f16<<<blk, 256, 0, stream>>>(w, wq, wn / 4);
        blk = (N / 4 + 255) / 256; if (blk > 2048) blk = 2048;
        quant_f32_to_f16<<<blk, 256, 0, stream>>>(b, bq, N / 4);

        dim3 grid((M / 128) * (N / 128));
        gemm_f16_qat<<<grid, 256, 0, stream>>>(xq, wq, bq, out, M, N, K);
    } else {
        dim3 grid((N + 255) / 256, M);
        qat_gemm_naive<<<grid, 256, 0, stream>>>(x, w, b, out, M, N, K);
    }
}

// Round 2
// 296.159 us; speedup vs baseline: 1.5018x; 1.5018x over previous
//
#include <hip/hip_runtime.h>
#include <hip/hip_fp16.h>
#include <cstdint>
#include <cstddef>

#define GLOBAL_AS __attribute__((address_space(1)))
#define LDS_AS    __attribute__((address_space(3)))

typedef __attribute__((ext_vector_type(8))) _Float16 f16x8;
typedef __attribute__((ext_vector_type(4))) float    f32x4;

__device__ __forceinline__ void gload_lds16(const void* g, void* l) {
    __builtin_amdgcn_global_load_lds((const GLOBAL_AS void*)g,
                                     (LDS_AS void*)l, 16, 0, 0);
}

// fp16 quantizer == reference fp_quantize_ste(exp=5, sig=10): RNE + saturate.
__device__ __forceinline__ __half qcvt(float x) {
    x = fminf(fmaxf(x, -65504.f), 65504.f);
    return __float2half(x);   // v_cvt_f16_f32: RNE, subnormals handled
}

__global__ void quant_f32_to_f16(const float* __restrict__ in,
                                 __half* __restrict__ out, int n4) {
    const int stride = gridDim.x * blockDim.x;
    for (int i = blockIdx.x * blockDim.x + threadIdx.x; i < n4; i += stride) {
        const float4 f = reinterpret_cast<const float4*>(in)[i];
        union { __half h[4]; uint2 u; } p;
        p.h[0] = qcvt(f.x);
        p.h[1] = qcvt(f.y);
        p.h[2] = qcvt(f.z);
        p.h[3] = qcvt(f.w);
        reinterpret_cast<uint2*>(out)[i] = p.u;
    }
}

// ---------------------------------------------------------------------------
// 256x256 tile, BK=64, 8 waves (2M x 4N), 8-phase schedule (m201 template).
// A: MxK row-major fp16, B: NxK row-major fp16 (= W), C = A@B^T + bias (f32).
//
// LDS: [buf][op A/B][half][128x64] fp16, st_16x32 subtiled-XOR swizzled.
//   layout byte(r,c) = ((r>>4)*2+(c>>5))*1024 + (((r&15)*64+(c&31)*2) ^ (((r>>3)&1)<<5))
// global_load_lds writes linearly -> source address is inverse-permuted (m173).
//
// Quadrants per tile: q0=(A0,B0) q1=(A0,B1) q2=(A1,B1) q3=(A1,B0).
// Staging (1 half-tile = 2 loads/thread per phase), into just-freed slots:
//   q0: B0(t+1)->nxt   q1: A0(t+2)->cur   q2: B1(t+2)->cur   q3: A1(t+2)->cur
// vmcnt(6) at q3 confirms all of tile t+1 (3 half-tiles stay in flight).
// ---------------------------------------------------------------------------
__global__ __launch_bounds__(512, 2) void gemm_f16_8phase(
    const __half* __restrict__ A, const __half* __restrict__ B,
    const __half* __restrict__ bias, float* __restrict__ C,
    int M, int N, int K)
{
    __shared__ __align__(16) __half lds[2][2][2][8192];   // 128 KiB

    const int tid  = threadIdx.x;
    const int lane = tid & 63;
    const int wid  = tid >> 6;     // 8 waves
    const int wr   = wid >> 2;     // 0..1 (M)
    const int wc   = wid & 3;      // 0..3 (N)
    const int fr   = lane & 15;
    const int fq   = lane >> 4;

    // bijective XCD swizzle (m204)
    const int nwg = gridDim.x;
    const int qq = nwg >> 3, rr = nwg & 7;
    const int xcd = blockIdx.x & 7, idx = blockIdx.x >> 3;
    const int wgid = (xcd < rr ? xcd * (qq + 1)
                               : rr * (qq + 1) + (xcd - rr) * qq) + idx;
    const int nbn = N >> 8;
    const int tile_m = (wgid / nbn) << 8;
    const int tile_n = (wgid % nbn) << 8;

    // ---- staging source coords (inverse of LDS swizzle, per thread) ----
    const int wbyte = (lane * 16) ^ (((lane >> 5) & 1) << 5);
    const int srow  = ((wid >> 1) << 4) + (wbyte >> 6);   // 0..63
    const int scb   = ((wid & 1) << 6) + (wbyte & 63);    // col byte 0..127
    const char* gA0 = (const char*)A + (size_t)(tile_m + srow) * K * 2 + scb;
    const char* gB0 = (const char*)B + (size_t)(tile_n + srow) * K * 2 + scb;
    const size_t rstep = (size_t)64  * K * 2;   // +64 rows
    const size_t hstep = (size_t)128 * K * 2;   // +1 half (128 rows)
    const int ldst = tid * 16;                  // linear LDS dest byte

    // ---- fragment-read byte offsets (swizzled) ----
    const int woff  = (fr * 64 + fq * 16) ^ (((fr >> 3) & 1) << 5);
    const int aoff  = wr * 8192 + woff;     // + m*2048 + kk*1024
    const int boff  = wc * 4096 + woff;     // + n*2048 + kk*1024

    f32x4 acc[2][2][4][2];
#pragma unroll
    for (int qa = 0; qa < 2; ++qa)
#pragma unroll
        for (int qb = 0; qb < 2; ++qb)
#pragma unroll
            for (int m = 0; m < 4; ++m)
#pragma unroll
                for (int n = 0; n < 2; ++n)
                    acc[qa][qb][m][n] = (f32x4){0.f, 0.f, 0.f, 0.f};

    f16x8 af[4][2], bf[2][2];

#define STAGE_A(bufi, h, kt) do {                                          \
        char* l_ = (char*)(&lds[bufi][0][h][0]) + ldst;                    \
        const char* g_ = gA0 + (size_t)(kt) * 128 + ((h) ? hstep : 0);     \
        gload_lds16(g_, l_);                                               \
        gload_lds16(g_ + rstep, l_ + 8192);                                \
    } while (0)

#define STAGE_B(bufi, h, kt) do {                                          \
        char* l_ = (char*)(&lds[bufi][1][h][0]) + ldst;                    \
        const char* g_ = gB0 + (size_t)(kt) * 128 + ((h) ? hstep : 0);     \
        gload_lds16(g_, l_);                                               \
        gload_lds16(g_ + rstep, l_ + 8192);                                \
    } while (0)

#define LDA(bufi, qa) do {                                                 \
        const char* lb_ = (const char*)(&lds[bufi][0][qa][0]) + aoff;      \
        _Pragma("unroll")                                                  \
        for (int m_ = 0; m_ < 4; ++m_) {                                   \
            af[m_][0] = *(const f16x8*)(lb_ + m_ * 2048);                  \
            af[m_][1] = *(const f16x8*)(lb_ + m_ * 2048 + 1024);           \
        }                                                                  \
    } while (0)

#define LDB(bufi, hb) do {                                                 \
        const char* lb_ = (const char*)(&lds[bufi][1][hb][0]) + boff;      \
        _Pragma("unroll")                                                  \
        for (int n_ = 0; n_ < 2; ++n_) {                                   \
            bf[n_][0] = *(const f16x8*)(lb_ + n_ * 2048);                  \
            bf[n_][1] = *(const f16x8*)(lb_ + n_ * 2048 + 1024);           \
        }                                                                  \
    } while (0)

#define MMA(qa, qb)                                                        \
    __builtin_amdgcn_s_setprio(1);                                         \
    _Pragma("unroll")                                                      \
    for (int m_ = 0; m_ < 4; ++m_) {                                       \
        _Pragma("unroll")                                                  \
        for (int n_ = 0; n_ < 2; ++n_) {                                   \
            acc[qa][qb][m_][n_] = __builtin_amdgcn_mfma_f32_16x16x32_f16(  \
                af[m_][0], bf[n_][0], acc[qa][qb][m_][n_], 0, 0, 0);       \
            acc[qa][qb][m_][n_] = __builtin_amdgcn_mfma_f32_16x16x32_f16(  \
                af[m_][1], bf[n_][1], acc[qa][qb][m_][n_], 0, 0, 0);       \
        }                                                                  \
    }                                                                      \
    __builtin_amdgcn_s_setprio(0);

#define PH_BAR1()                                                          \
    asm volatile("" ::: "memory");                                         \
    __builtin_amdgcn_s_barrier();                                          \
    asm volatile("s_waitcnt lgkmcnt(0)" ::: "memory")

#define PH_BAR2()                                                          \
    asm volatile("" ::: "memory");                                         \
    __builtin_amdgcn_s_barrier()

#define TILE_FULL(cur, nxt, kt)                                            \
    LDA(cur, 0); LDB(cur, 0); STAGE_B(nxt, 0, (kt) + 1);                   \
    PH_BAR1(); MMA(0, 0); PH_BAR2();                                       \
    LDB(cur, 1); STAGE_A(cur, 0, (kt) + 2);                                \
    PH_BAR1(); MMA(0, 1); PH_BAR2();                                       \
    LDA(cur, 1); STAGE_B(cur, 1, (kt) + 2);                                \
    PH_BAR1(); MMA(1, 1); PH_BAR2();                                       \
    LDB(cur, 0); STAGE_A(cur, 1, (kt) + 2);                                \
    asm volatile("s_waitcnt vmcnt(6)" ::: "memory");                       \
    PH_BAR1(); MMA(1, 0); PH_BAR2();

    // ---- prologue: tile0 (A0,B0,B1,A1) + tile1 (A0,B1,A1); B0(1) in-loop
    STAGE_A(0, 0, 0); STAGE_B(0, 0, 0); STAGE_B(0, 1, 0); STAGE_A(0, 1, 0);
    STAGE_A(1, 0, 1); STAGE_B(1, 1, 1); STAGE_A(1, 1, 1);
    asm volatile("s_waitcnt vmcnt(6)" ::: "memory");   // confirm tile 0
    __builtin_amdgcn_s_barrier();

    const int nt = K >> 6;              // even, >= 4 (guarded by launcher)
    for (int kt = 0; kt + 3 < nt; kt += 2) {
        TILE_FULL(0, 1, kt);
        TILE_FULL(1, 0, kt + 1);
    }

    // ---- tile nt-2 (buf0): only B0(nt-1) left to stage; drain at q3 ----
    LDA(0, 0); LDB(0, 0); STAGE_B(1, 0, nt - 1);
    PH_BAR1(); MMA(0, 0); PH_BAR2();
    LDB(0, 1);
    PH_BAR1(); MMA(0, 1); PH_BAR2();
    LDA(0, 1);
    PH_BAR1(); MMA(1, 1); PH_BAR2();
    LDB(0, 0);
    asm volatile("s_waitcnt vmcnt(0)" ::: "memory");
    PH_BAR1(); MMA(1, 0); PH_BAR2();

    // ---- tile nt-1 (buf1): pure compute ----
    LDA(1, 0); LDB(1, 0);
    PH_BAR1(); MMA(0, 0); PH_BAR2();
    LDB(1, 1);
    PH_BAR1(); MMA(0, 1); PH_BAR2();
    LDA(1, 1);
    PH_BAR1(); MMA(1, 1); PH_BAR2();
    LDB(1, 0);
    PH_BAR1(); MMA(1, 0);

    // ---- epilogue: C/D layout col=lane&15, row=fq*4+reg (m89-verified) ----
    float bv[2][2];
#pragma unroll
    for (int qb = 0; qb < 2; ++qb)
#pragma unroll
        for (int n = 0; n < 2; ++n)
            bv[qb][n] = __half2float(
                bias[tile_n + qb * 128 + wc * 32 + n * 16 + fr]);

#pragma unroll
    for (int qa = 0; qa < 2; ++qa)
#pragma unroll
        for (int qb = 0; qb < 2; ++qb)
#pragma unroll
            for (int m = 0; m < 4; ++m)
#pragma unroll
                for (int n = 0; n < 2; ++n) {
                    const int col = tile_n + qb * 128 + wc * 32 + n * 16 + fr;
                    const int rowb = tile_m + qa * 128 + wr * 64 + m * 16 + fq * 4;
#pragma unroll
                    for (int r = 0; r < 4; ++r)
                        C[(size_t)(rowb + r) * N + col] =
                            acc[qa][qb][m][n][r] + bv[qb][n];
                }

#undef STAGE_A
#undef STAGE_B
#undef LDA
#undef LDB
#undef MMA
#undef PH_BAR1
#undef PH_BAR2
#undef TILE_FULL
}

// ---------------------------------------------------------------------------
// Insurance fallback (shape or ws mismatch): fused naive, slow but correct.
// ---------------------------------------------------------------------------
__global__ void qat_gemm_naive(const float* __restrict__ A,
                               const float* __restrict__ B,
                               const float* __restrict__ bias,
                               float* __restrict__ C, int M, int N, int K) {
    const int col = blockIdx.x * blockDim.x + threadIdx.x;
    const int row = blockIdx.y;
    if (col >= N || row >= M) return;
    float s = 0.f;
    for (int k = 0; k < K; ++k) {
        float a = __half2float(qcvt(A[(size_t)row * K + k]));
        float b = __half2float(qcvt(B[(size_t)col * K + k]));
        s += a * b;
    }
    C[(size_t)row * N + col] = s + __half2float(qcvt(bias[col]));
}

// ---------------------------------------------------------------------------
extern "C" void kernel_launch(void* const* d_in, const int* in_sizes, int n_in,
                              void* d_out, int out_size, void* d_ws,
                              size_t ws_size, hipStream_t stream) {
    const float* x = (const float*)d_in[0];
    const float* w = (const float*)d_in[1];
    const float* b = (const float*)d_in[2];
    float* out = (float*)d_out;

    const int xn = in_sizes[0];     // M*K
    const int wn = in_sizes[1];     // N*K
    const int N  = in_sizes[2];     // 4096
    const int K  = wn / N;          // 4096
    const int M  = xn / K;          // 8192

    const size_t need = (size_t)(xn + wn + N) * sizeof(__half);
    const bool ok = (M % 256 == 0) && (N % 256 == 0) &&
                    (K % 128 == 0) && (K >= 256);

    if (ws_size >= need && ok) {
        __half* xq = (__half*)d_ws;
        __half* wq = xq + xn;
        __half* bq = wq + wn;

        int blk;
        blk = (xn / 4 + 255) / 256; if (blk > 2048) blk = 2048;
        quant_f32_to_f16<<<blk, 256, 0, stream>>>(x, xq, xn / 4);
        blk = (wn / 4 + 255) / 256; if (blk > 2048) blk = 2048;
        quant_f32_to_f16<<<blk, 256, 0, stream>>>(w, wq, wn / 4);
        blk = (N / 4 + 255) / 256; if (blk > 2048) blk = 2048;
        quant_f32_to_f16<<<blk, 256, 0, stream>>>(b, bq, N / 4);

        dim3 grid((M / 256) * (N / 256));
        gemm_f16_8phase<<<grid, 512, 0, stream>>>(xq, wq, bq, out, M, N, K);
    } else {
        dim3 grid((N + 255) / 256, M);
        qat_gemm_naive<<<grid, 256, 0, stream>>>(x, w, b, out, M, N, K);
    }
}